// Round 3
// baseline (172235.950 us; speedup 1.0000x reference)
//
#include <hip/hip_runtime.h>
#include <cstdint>
#include <cstddef>

// ---------------------------------------------------------------------------
// Tacotron2-style decoder. Persistent plain-launch kernel (256 blocks x 256
// threads, guaranteed co-resident: 1 block/CU) with a manual device-scope
// grid barrier. Prologue (zero + prenet + memproj) runs as 3 small one-time
// kernels. Phase bodies are verbatim the round-1 (passing) kernels.
// fp32 throughout. Threefry partitionable PRNG (verified round 1).
// ---------------------------------------------------------------------------

#define BB   32
#define SS   512
#define EMBD 256
#define MELD 80
#define PRED 256
#define RNND 1024
#define ATTD 128
#define TT   400
#define NBLK 256

// ------------------------------- threefry ---------------------------------
__device__ __forceinline__ void tf_block(uint32_t k0, uint32_t k1,
                                         uint32_t x0, uint32_t x1,
                                         uint32_t& o0, uint32_t& o1) {
  uint32_t ks2 = k0 ^ k1 ^ 0x1BD11BDAu;
  x0 += k0; x1 += k1;
#define TFR(r) { x0 += x1; x1 = (x1 << (r)) | (x1 >> (32 - (r))); x1 ^= x0; }
  TFR(13) TFR(15) TFR(26) TFR(6)
  x0 += k1;  x1 += ks2 + 1u;
  TFR(17) TFR(29) TFR(16) TFR(24)
  x0 += ks2; x1 += k0 + 2u;
  TFR(13) TFR(15) TFR(26) TFR(6)
  x0 += k0;  x1 += k1 + 3u;
  TFR(17) TFR(29) TFR(16) TFR(24)
  x0 += k1;  x1 += ks2 + 4u;
  TFR(13) TFR(15) TFR(26) TFR(6)
  x0 += ks2; x1 += k0 + 5u;
#undef TFR
  o0 = x0; o1 = x1;
}

__device__ __forceinline__ void subkey(int t, int j, uint32_t& k0, uint32_t& k1) {
  uint32_t a, b;
  tf_block(0u, 42u, 0u, (uint32_t)t, a, b);   // fold_in
  tf_block(a, b, 0u, (uint32_t)j, k0, k1);    // partitionable split
}

__device__ __forceinline__ bool keep_draw(uint32_t k0, uint32_t k1,
                                          uint32_t idx, float pkeep) {
  uint32_t o0, o1;
  tf_block(k0, k1, 0u, idx, o0, o1);
  uint32_t bits = o0 ^ o1;
  float u = __uint_as_float((bits >> 9) | 0x3f800000u) - 1.0f;
  return u < pkeep;
}

__device__ __forceinline__ float sigm(float x) { return 1.0f / (1.0f + expf(-x)); }

// --------------------------- manual grid barrier ---------------------------
// Monotonic-generation barrier; cnt self-resets. Device (agent) scope atomics
// handle cross-XCD L2 non-coherence. Init kernel zeroes cnt/gen each call.
__device__ __forceinline__ void gsync(uint32_t* cnt, uint32_t* gen, uint32_t& lgen) {
  __threadfence();             // agent-scope fence: prior writes visible
  __syncthreads();
  lgen += 1u;
  if (threadIdx.x == 0) {
    uint32_t a = __hip_atomic_fetch_add(cnt, 1u, __ATOMIC_ACQ_REL,
                                        __HIP_MEMORY_SCOPE_AGENT);
    if (a == (uint32_t)(NBLK - 1)) {
      __hip_atomic_store(cnt, 0u, __ATOMIC_RELAXED, __HIP_MEMORY_SCOPE_AGENT);
      __hip_atomic_store(gen, lgen, __ATOMIC_RELEASE, __HIP_MEMORY_SCOPE_AGENT);
    } else {
      while (__hip_atomic_load(gen, __ATOMIC_ACQUIRE,
                               __HIP_MEMORY_SCOPE_AGENT) < lgen) {
        __builtin_amdgcn_s_sleep(2);
      }
    }
  }
  __syncthreads();
}

// ------------------------------ init ---------------------------------------
__global__ void init_kernel(float* statebase, int nstate, uint32_t* barrier2) {
  int i = blockIdx.x * blockDim.x + threadIdx.x;
  if (i < nstate) statebase[i] = 0.0f;
  if (i == 0) { barrier2[0] = 0u; barrier2[1] = 0u; }
}

// --------------------------- prenet (all t) --------------------------------
__global__ __launch_bounds__(256) void prenet_kernel(
    const float* __restrict__ tmels, const float* __restrict__ W1,
    const float* __restrict__ b1, const float* __restrict__ W2,
    const float* __restrict__ b2, float* __restrict__ P_all) {
  __shared__ float melsh[MELD];
  __shared__ float h1sh[PRED];
  int blk = blockIdx.x, tid = threadIdx.x;
  int t = blk >> 5, b = blk & 31;
  if (tid < MELD)
    melsh[tid] = (t == 0) ? 0.0f : tmels[((size_t)b * TT + (t - 1)) * MELD + tid];
  __syncthreads();
  uint32_t k10, k11, k20, k21;
  subkey(t, 0, k10, k11);
  subkey(t, 1, k20, k21);
  {
    const float* wr = W1 + (size_t)tid * MELD;
    float acc = b1[tid];
    for (int m = 0; m < MELD; ++m) acc += melsh[m] * wr[m];
    acc = fmaxf(acc, 0.0f);
    bool kp = keep_draw(k10, k11, (uint32_t)(b * PRED + tid), 0.5f);
    h1sh[tid] = kp ? (acc / 0.5f) : 0.0f;
  }
  __syncthreads();
  {
    const float* wr = W2 + (size_t)tid * PRED;
    float acc = b2[tid];
    for (int k = 0; k < PRED; ++k) acc += h1sh[k] * wr[k];
    acc = fmaxf(acc, 0.0f);
    bool kp = keep_draw(k20, k21, (uint32_t)(b * PRED + tid), 0.5f);
    P_all[((size_t)t * BB + b) * PRED + tid] = kp ? (acc / 0.5f) : 0.0f;
  }
}

// ------------------------------ mem_proj -----------------------------------
__global__ __launch_bounds__(128) void memproj_kernel(
    const float* __restrict__ emb, const float* __restrict__ Wmem,
    float* __restrict__ mp) {
  __shared__ float esh[EMBD];
  int blk = blockIdx.x, tid = threadIdx.x;   // blk = b*S + s
  const float* er = emb + (size_t)blk * EMBD;
  esh[tid] = er[tid];
  esh[tid + 128] = er[tid + 128];
  __syncthreads();
  const float4* wr = (const float4*)(Wmem + (size_t)tid * EMBD);
  const float4* xr = (const float4*)esh;
  float acc = 0.0f;
  for (int k4 = 0; k4 < EMBD / 4; ++k4) {
    float4 w = wr[k4], x = xr[k4];
    acc += w.x * x.x + w.y * x.y + w.z * x.z + w.w * x.w;
  }
  mp[(size_t)blk * ATTD + tid] = acc;
}

// ------------------------------- params ------------------------------------
struct DecParams {
  const float *emb, *tmels;
  const float *Wih_pre, *Whh_pre, *bih_pre, *bhh_pre;
  const float *Wq, *conv_w, *Wloc, *vvec;
  const float *Wih_post, *Whh_post, *bih_post, *bhh_post;
  const float *Wmel, *bmel, *Wstop, *bstop;
  float *out;
  float *memproj, *P_all;
  float *Apre0, *Apre1, *Bpre0, *Bpre1;
  float *Apost0, *Apost1, *Bpost0, *Bpost1;
  float *ctx0, *ctx1, *aw0, *aw1, *asum0, *asum1;
  float *qbuf, *energ;
  uint32_t *barrier2;
};

// ---------------------------------------------------------------------------
__global__ __launch_bounds__(256) void decoder_persistent(DecParams p) {
  __shared__ __align__(16) float smem[8768];   // 34.25 KB, unioned per phase
  const int blk = blockIdx.x;
  const int tid = threadIdx.x;
  uint32_t* bcnt = p.barrier2;
  uint32_t* bgen = p.barrier2 + 1;
  uint32_t lgen = 0u;

  for (int t = 0; t <= TT; ++t) {
    const int rr = t & 1;
    const float* Apre_r  = rr ? p.Apre1  : p.Apre0;
    const float* Bpre_r  = rr ? p.Bpre1  : p.Bpre0;
    float*       Apre_w  = rr ? p.Apre0  : p.Apre1;
    float*       Bpre_w  = rr ? p.Bpre0  : p.Bpre1;
    const float* Apost_r = rr ? p.Apost0 : p.Apost1;   // [1-rr]
    const float* Bpost_r = rr ? p.Bpost0 : p.Bpost1;
    float*       Apost_w = rr ? p.Apost1 : p.Apost0;   // [rr]
    float*       Bpost_w = rr ? p.Bpost1 : p.Bpost0;
    const float* ctx_r   = rr ? p.ctx1   : p.ctx0;
    float*       ctx_w   = rr ? p.ctx0   : p.ctx1;
    const float* aw_r    = rr ? p.aw1    : p.aw0;
    float*       aw_w    = rr ? p.aw0    : p.aw1;
    const float* asum_r  = rr ? p.asum1  : p.asum0;
    float*       asum_w  = rr ? p.asum0  : p.asum1;

    // ---------------- phase A: lstm1(t) [blk<128] + lstm2(t-1) -------------
    {
      const bool is1 = (blk < 128);
      const bool active = is1 ? (t < TT) : (t > 0);
      if (active) {
        float (*xs)[256] = (float (*)[256])smem;
        const int tstep = is1 ? t : (t - 1);
        const int hb = (is1 ? blk : blk - 128) * 8;
        const int col = tid & 31;
        const int lq  = tid >> 5;
        const int b0  = lq * 4;
        const int gate = col >> 3;
        const int hl   = col & 7;
        const int gcol = gate * RNND + hb + hl;
        const int nchunks = is1 ? 6 : 9;

        float acc0 = 0.f, acc1 = 0.f, acc2 = 0.f, acc3 = 0.f;

        for (int ch = 0; ch < nchunks; ++ch) {
          __syncthreads();
#pragma unroll
          for (int it = 0; it < 8; ++it) {
            int flat = tid + it * 256;
            int bb = flat >> 6;
            int k4 = flat & 63;
            const float* src;
            if (is1) {
              if (ch == 0)      src = p.P_all + ((size_t)t * BB + bb) * PRED;
              else if (ch == 1) src = ctx_r + (size_t)bb * EMBD;
              else              src = Apre_r + (size_t)bb * RNND + (ch - 2) * 256;
            } else {
              if (ch < 4)       src = Bpre_r + (size_t)bb * RNND + ch * 256;
              else if (ch == 4) src = ctx_r + (size_t)bb * EMBD;
              else              src = Apost_r + (size_t)bb * RNND + (ch - 5) * 256;
            }
            float4 v4 = *(((const float4*)src) + k4);
            *(((float4*)&xs[bb][0]) + k4) = v4;
          }
          __syncthreads();

          const float* wrow;
          if (is1) wrow = (ch < 2) ? (p.Wih_pre + (size_t)gcol * 512 + ch * 256)
                                   : (p.Whh_pre + (size_t)gcol * 1024 + (ch - 2) * 256);
          else     wrow = (ch < 5) ? (p.Wih_post + (size_t)gcol * 1280 + ch * 256)
                                   : (p.Whh_post + (size_t)gcol * 1024 + (ch - 5) * 256);
          const float4* w4p = (const float4*)wrow;
#pragma unroll 8
          for (int k4 = 0; k4 < 64; ++k4) {
            float4 w = w4p[k4];
            float4 xa = *(((const float4*)&xs[b0 + 0][0]) + k4);
            float4 xb = *(((const float4*)&xs[b0 + 1][0]) + k4);
            float4 xc = *(((const float4*)&xs[b0 + 2][0]) + k4);
            float4 xd = *(((const float4*)&xs[b0 + 3][0]) + k4);
            acc0 += w.x * xa.x + w.y * xa.y + w.z * xa.z + w.w * xa.w;
            acc1 += w.x * xb.x + w.y * xb.y + w.z * xb.z + w.w * xb.w;
            acc2 += w.x * xc.x + w.y * xc.y + w.z * xc.z + w.w * xc.w;
            acc3 += w.x * xd.x + w.y * xd.y + w.z * xd.z + w.w * xd.w;
          }
        }

        float bsum = is1 ? (p.bih_pre[gcol] + p.bhh_pre[gcol])
                         : (p.bih_post[gcol] + p.bhh_post[gcol]);
        acc0 += bsum; acc1 += bsum; acc2 += bsum; acc3 += bsum;

        int lane = tid & 63;
        float f0 = __shfl(acc0, lane + 8),  f1 = __shfl(acc1, lane + 8);
        float f2 = __shfl(acc2, lane + 8),  f3 = __shfl(acc3, lane + 8);
        float g0 = __shfl(acc0, lane + 16), g1 = __shfl(acc1, lane + 16);
        float g2 = __shfl(acc2, lane + 16), g3 = __shfl(acc3, lane + 16);
        float q0 = __shfl(acc0, lane + 24), q1 = __shfl(acc1, lane + 24);
        float q2 = __shfl(acc2, lane + 24), q3 = __shfl(acc3, lane + 24);

        if (gate == 0) {
          uint32_t kk0, kk1;
          subkey(tstep, is1 ? 2 : 3, kk0, kk1);
          const int h = hb + hl;
          const float* Bold = is1 ? Bpre_r : Bpost_r;
          float* Aw = is1 ? Apre_w : Apost_w;
          float* Bw = is1 ? Bpre_w : Bpost_w;
          float ia[4] = {acc0, acc1, acc2, acc3};
          float fa[4] = {f0, f1, f2, f3};
          float ga[4] = {g0, g1, g2, g3};
          float oa[4] = {q0, q1, q2, q3};
#pragma unroll
          for (int i2 = 0; i2 < 4; ++i2) {
            int bb = b0 + i2;
            float iv = sigm(ia[i2]);
            float fv = sigm(fa[i2]);
            float gv = tanhf(ga[i2]);
            float ov = sigm(oa[i2]);
            float c_new = fv * Bold[(size_t)bb * RNND + h] + iv * gv;
            float h_new = ov * tanhf(c_new);
            bool kp = keep_draw(kk0, kk1, (uint32_t)(bb * RNND + h), 0.9f);
            Aw[(size_t)bb * RNND + h] = kp ? (h_new / 0.9f) : 0.0f;
            Bw[(size_t)bb * RNND + h] = c_new;
          }
        }
      }
    }
    gsync(bcnt, bgen, lgen);

    // ---------------- phase Q: q proj (blk 0-15) + outproj t-1 (16-47) -----
    if (blk < 16) {
      if (t < TT) {
        float* xsh = smem;   // 2 x 1024
        int b2 = blk * 2;
        for (int flat = tid; flat < 2 * RNND; flat += 256)
          xsh[flat] = Bpre_w[(size_t)(b2 + (flat >> 10)) * RNND + (flat & 1023)];
        __syncthreads();
        int a = tid & 127, bh = tid >> 7;
        const float4* wr = (const float4*)(p.Wq + (size_t)a * RNND);
        const float4* xr = ((const float4*)xsh) + bh * (RNND / 4);
        float acc = 0.0f;
        for (int k4 = 0; k4 < RNND / 4; ++k4) {
          float4 w = wr[k4], x = xr[k4];
          acc += w.x * x.x + w.y * x.y + w.z * x.z + w.w * x.w;
        }
        p.qbuf[(size_t)(b2 + bh) * ATTD + a] = acc;
      }
    } else if (blk < 48) {
      if (t > 0) {
        int b = blk - 16;
        int o = tid;
        int t_prev = t - 1;
        if (o <= 80) {
          const float* wrow = (o < 80) ? (p.Wmel + (size_t)o * 1280) : p.Wstop;
          const float4* w4 = (const float4*)wrow;
          const float4* x4 = (const float4*)(Bpost_w + (size_t)b * RNND);
          float acc = 0.0f;
          for (int k4 = 0; k4 < RNND / 4; ++k4) {
            float4 w = w4[k4], x = x4[k4];
            acc += w.x * x.x + w.y * x.y + w.z * x.z + w.w * x.w;
          }
          const float4* w4b = (const float4*)(wrow + RNND);
          const float4* c4 = (const float4*)(ctx_r + (size_t)b * EMBD);
          for (int k4 = 0; k4 < EMBD / 4; ++k4) {
            float4 w = w4b[k4], x = c4[k4];
            acc += w.x * x.x + w.y * x.y + w.z * x.z + w.w * x.w;
          }
          acc += (o < 80) ? p.bmel[o] : p.bstop[0];
          float val = sigm(acc);
          if (o < 80)
            p.out[(size_t)b * (TT * MELD) + (size_t)t_prev * MELD + o] = val;
          else
            p.out[(size_t)BB * TT * MELD + (size_t)b * TT + t_prev] = val;
        }
      }
    }
    gsync(bcnt, bgen, lgen);

    // ---------------- phase E: energies (256 blocks) -----------------------
    if (t < TT) {
      float* qsh   = smem;          // 128
      float* vsh   = smem + 128;    // 128
      float* awin  = smem + 256;    // 94 (pad 96)
      float* aswin = smem + 352;    // 94 (pad 96)
      float* wlocs = smem + 448;    // 128*33 = 4224
      float* convs = smem + 4672;   // 32*62 = 1984
      float* locs  = smem + 6656;   // 64*33 = 2112 -> ends at 8768
      int b = blk >> 3, st = blk & 7, s0 = st * 64;
      __syncthreads();
      if (tid < ATTD) { qsh[tid] = p.qbuf[b * ATTD + tid]; vsh[tid] = p.vvec[tid]; }
      if (tid < 94) {
        int sg = s0 - 15 + tid;
        bool ok = (sg >= 0) && (sg < SS);
        awin[tid]  = ok ? aw_r[b * SS + sg]   : 0.0f;
        aswin[tid] = ok ? asum_r[b * SS + sg] : 0.0f;
      }
      for (int idx = tid; idx < ATTD * 32; idx += 256) {
        int a = idx >> 5, c = idx & 31;
        wlocs[a * 33 + c] = p.Wloc[a * 32 + c];
      }
      for (int idx = tid; idx < 32 * 62; idx += 256) convs[idx] = p.conv_w[idx];
      __syncthreads();
      for (int idx = tid; idx < 64 * 32; idx += 256) {
        int sl = idx & 63, c = idx >> 6;
        const float* cw0 = &convs[c * 62];
        const float* cw1 = &convs[c * 62 + 31];
        float acc = 0.0f;
        for (int k = 0; k < 31; ++k)
          acc += cw0[k] * aswin[sl + k] + cw1[k] * awin[sl + k];
        locs[sl * 33 + c] = acc;
      }
      __syncthreads();
      int sl = tid >> 2, aq = tid & 3, sg = s0 + sl;
      const float* mp = p.memproj + ((size_t)b * SS + sg) * ATTD;
      float acc = 0.0f;
      const float* ls = &locs[sl * 33];
      for (int j = 0; j < 32; ++j) {
        int a = j * 4 + aq;
        const float* wl = &wlocs[a * 33];
        float lp = 0.0f;
#pragma unroll 8
        for (int c = 0; c < 32; ++c) lp += ls[c] * wl[c];
        acc += vsh[a] * tanhf(qsh[a] + mp[a] + lp);
      }
      acc += __shfl_down(acc, 2);
      acc += __shfl_down(acc, 1);
      if (aq == 0) p.energ[b * SS + sg] = acc;
    }
    gsync(bcnt, bgen, lgen);

    // ---------------- phase C: softmax + context (blk < 128) ---------------
    if (t < TT && blk < 128) {
      float* psh   = smem;          // 512
      float* red   = smem + 512;    // 256
      float (*cpart)[64] = (float (*)[64])(smem + 768);  // 4 x 64
      int b = blk >> 2, ec = blk & 3;
      float e1 = p.energ[b * SS + tid], e2 = p.energ[b * SS + 256 + tid];
      red[tid] = fmaxf(e1, e2);
      __syncthreads();
      for (int s = 128; s > 0; s >>= 1) {
        if (tid < s) red[tid] = fmaxf(red[tid], red[tid + s]);
        __syncthreads();
      }
      float mx = red[0];
      __syncthreads();
      float p1 = expf(e1 - mx), p2 = expf(e2 - mx);
      psh[tid] = p1; psh[tid + 256] = p2;
      red[tid] = p1 + p2;
      __syncthreads();
      for (int s = 128; s > 0; s >>= 1) {
        if (tid < s) red[tid] += red[tid + s];
        __syncthreads();
      }
      float inv = 1.0f / red[0];
      int el = tid & 63, sq = tid >> 6;
      int e = ec * 64 + el;
      float acc = 0.0f;
      const float* ebase = p.emb + ((size_t)b * SS) * EMBD + e;
      for (int s = sq * 128; s < sq * 128 + 128; ++s)
        acc += psh[s] * ebase[(size_t)s * EMBD];
      cpart[sq][el] = acc;
      __syncthreads();
      if (tid < 64)
        ctx_w[b * EMBD + ec * 64 + tid] =
            (cpart[0][tid] + cpart[1][tid] + cpart[2][tid] + cpart[3][tid]) * inv;
      if (ec == 0) {
        float a1 = p1 * inv, a2 = p2 * inv;
        aw_w[b * SS + tid] = a1;
        aw_w[b * SS + 256 + tid] = a2;
        asum_w[b * SS + tid] = asum_r[b * SS + tid] + a1;
        asum_w[b * SS + 256 + tid] = asum_r[b * SS + 256 + tid] + a2;
      }
    }
    gsync(bcnt, bgen, lgen);
  }
}

// ------------------------------- launch ------------------------------------
extern "C" void kernel_launch(void* const* d_in, const int* in_sizes, int n_in,
                              void* d_out, int out_size, void* d_ws, size_t ws_size,
                              hipStream_t stream) {
  DecParams hp;
  hp.emb      = (const float*)d_in[0];
  hp.tmels    = (const float*)d_in[1];
  const float* W1 = (const float*)d_in[2];
  const float* b1 = (const float*)d_in[3];
  const float* W2 = (const float*)d_in[4];
  const float* b2 = (const float*)d_in[5];
  hp.Wih_pre  = (const float*)d_in[6];
  hp.Whh_pre  = (const float*)d_in[7];
  hp.bih_pre  = (const float*)d_in[8];
  hp.bhh_pre  = (const float*)d_in[9];
  hp.Wq       = (const float*)d_in[10];
  const float* Wmem = (const float*)d_in[11];
  hp.conv_w   = (const float*)d_in[12];
  hp.Wloc     = (const float*)d_in[13];
  hp.vvec     = (const float*)d_in[14];
  hp.Wih_post = (const float*)d_in[15];
  hp.Whh_post = (const float*)d_in[16];
  hp.bih_post = (const float*)d_in[17];
  hp.bhh_post = (const float*)d_in[18];
  hp.Wmel     = (const float*)d_in[19];
  hp.bmel     = (const float*)d_in[20];
  hp.Wstop    = (const float*)d_in[21];
  hp.bstop    = (const float*)d_in[22];
  hp.out = (float*)d_out;

  float* w = (float*)d_ws;
  size_t off = 0;
  auto carve = [&](size_t n) {
    float* ptr = w + off;
    off += (n + 63) & ~((size_t)63);
    return ptr;
  };
  hp.memproj = carve((size_t)BB * SS * ATTD);
  hp.P_all   = carve((size_t)TT * BB * PRED);
  size_t state_begin = off;
  hp.Apre0  = carve(BB * RNND); hp.Apre1  = carve(BB * RNND);
  hp.Bpre0  = carve(BB * RNND); hp.Bpre1  = carve(BB * RNND);
  hp.Apost0 = carve(BB * RNND); hp.Apost1 = carve(BB * RNND);
  hp.Bpost0 = carve(BB * RNND); hp.Bpost1 = carve(BB * RNND);
  hp.ctx0   = carve(BB * EMBD); hp.ctx1   = carve(BB * EMBD);
  hp.aw0    = carve(BB * SS);   hp.aw1    = carve(BB * SS);
  hp.asum0  = carve(BB * SS);   hp.asum1  = carve(BB * SS);
  size_t state_end = off;
  hp.qbuf  = carve(BB * ATTD);
  hp.energ = carve(BB * SS);
  hp.barrier2 = (uint32_t*)carve(64);
  int nstate = (int)(state_end - state_begin);

  init_kernel<<<(nstate + 255) / 256, 256, 0, stream>>>(
      w + state_begin, nstate, hp.barrier2);
  prenet_kernel<<<TT * BB, 256, 0, stream>>>(hp.tmels, W1, b1, W2, b2, hp.P_all);
  memproj_kernel<<<BB * SS, 128, 0, stream>>>(hp.emb, Wmem, hp.memproj);
  decoder_persistent<<<NBLK, 256, 0, stream>>>(hp);

  (void)in_sizes; (void)n_in; (void)out_size; (void)ws_size;
}

// Round 5
// 95091.016 us; speedup vs baseline: 1.8113x; 1.8113x over previous
//
#include <hip/hip_runtime.h>
#include <cstdint>
#include <cstddef>

// ---------------------------------------------------------------------------
// Tacotron2-style decoder. Persistent plain-launch kernel (256 blocks x 256
// threads) with a FENCE-FREE grid barrier (flags + collector block, all
// sc0/sc1 LLC-coherent ops) so per-XCD L2 is never invalidated: weights,
// memproj, emb stay L2-resident across all 400 steps. All cross-block state
// moves via sc0/sc1 loads/stores. 3 barriers/step. fp32 throughout.
// ---------------------------------------------------------------------------

#define BB   32
#define SS   512
#define EMBD 256
#define MELD 80
#define PRED 256
#define RNND 1024
#define ATTD 128
#define TT   400
#define NBLK 256

typedef float nfloat4 __attribute__((ext_vector_type(4)));

// ------------------------------- threefry ---------------------------------
__device__ __forceinline__ void tf_block(uint32_t k0, uint32_t k1,
                                         uint32_t x0, uint32_t x1,
                                         uint32_t& o0, uint32_t& o1) {
  uint32_t ks2 = k0 ^ k1 ^ 0x1BD11BDAu;
  x0 += k0; x1 += k1;
#define TFR(r) { x0 += x1; x1 = (x1 << (r)) | (x1 >> (32 - (r))); x1 ^= x0; }
  TFR(13) TFR(15) TFR(26) TFR(6)
  x0 += k1;  x1 += ks2 + 1u;
  TFR(17) TFR(29) TFR(16) TFR(24)
  x0 += ks2; x1 += k0 + 2u;
  TFR(13) TFR(15) TFR(26) TFR(6)
  x0 += k0;  x1 += k1 + 3u;
  TFR(17) TFR(29) TFR(16) TFR(24)
  x0 += k1;  x1 += ks2 + 4u;
  TFR(13) TFR(15) TFR(26) TFR(6)
  x0 += ks2; x1 += k0 + 5u;
#undef TFR
  o0 = x0; o1 = x1;
}

__device__ __forceinline__ void subkey(int t, int j, uint32_t& k0, uint32_t& k1) {
  uint32_t a, b;
  tf_block(0u, 42u, 0u, (uint32_t)t, a, b);   // fold_in
  tf_block(a, b, 0u, (uint32_t)j, k0, k1);    // partitionable split
}

__device__ __forceinline__ bool keep_draw(uint32_t k0, uint32_t k1,
                                          uint32_t idx, float pkeep) {
  uint32_t o0, o1;
  tf_block(k0, k1, 0u, idx, o0, o1);
  uint32_t bits = o0 ^ o1;
  float u = __uint_as_float((bits >> 9) | 0x3f800000u) - 1.0f;
  return u < pkeep;
}

__device__ __forceinline__ float sigm(float x) { return 1.0f / (1.0f + expf(-x)); }

// ----------------------- LLC-coherent (sc0 sc1) ops ------------------------
__device__ __forceinline__ float llc_load1(const float* p) {
  float v;
  asm volatile("global_load_dword %0, %1, off sc0 sc1\ns_waitcnt vmcnt(0)"
               : "=v"(v) : "v"(p) : "memory");
  return v;
}
__device__ __forceinline__ void llc_load1x2(const float* p0, const float* p1,
                                            float& v0, float& v1) {
  asm volatile(
      "global_load_dword %0, %2, off sc0 sc1\n"
      "global_load_dword %1, %3, off sc0 sc1\n"
      "s_waitcnt vmcnt(0)"
      : "=&v"(v0), "=&v"(v1) : "v"(p0), "v"(p1) : "memory");
}
__device__ __forceinline__ void llc_load1x4(const float* p0, const float* p1,
                                            const float* p2, const float* p3,
                                            float& v0, float& v1, float& v2, float& v3) {
  asm volatile(
      "global_load_dword %0, %4, off sc0 sc1\n"
      "global_load_dword %1, %5, off sc0 sc1\n"
      "global_load_dword %2, %6, off sc0 sc1\n"
      "global_load_dword %3, %7, off sc0 sc1\n"
      "s_waitcnt vmcnt(0)"
      : "=&v"(v0), "=&v"(v1), "=&v"(v2), "=&v"(v3)
      : "v"(p0), "v"(p1), "v"(p2), "v"(p3) : "memory");
}
__device__ __forceinline__ float4 llc_load4(const float4* p) {
  float4 v;
  asm volatile("global_load_dwordx4 %0, %1, off sc0 sc1\ns_waitcnt vmcnt(0)"
               : "=v"(v) : "v"(p) : "memory");
  return v;
}
__device__ __forceinline__ void llc_store1(float* p, float v) {
  asm volatile("global_store_dword %0, %1, off sc0 sc1" :: "v"(p), "v"(v) : "memory");
}
__device__ __forceinline__ uint32_t llc_loadu(const uint32_t* p) {
  uint32_t v;
  asm volatile("global_load_dword %0, %1, off sc0 sc1\ns_waitcnt vmcnt(0)"
               : "=v"(v) : "v"(p) : "memory");
  return v;
}
__device__ __forceinline__ void llc_storeu(uint32_t* p, uint32_t v) {
  asm volatile("global_store_dword %0, %1, off sc0 sc1" :: "v"(p), "v"(v) : "memory");
}
// issue 8 x dwordx4 sc-loads WITHOUT wait (prefetch); pair with waitv0()
__device__ __forceinline__ void llc_issue8(
    const float4* a0, const float4* a1, const float4* a2, const float4* a3,
    const float4* a4, const float4* a5, const float4* a6, const float4* a7,
    float4& v0, float4& v1, float4& v2, float4& v3,
    float4& v4, float4& v5, float4& v6, float4& v7) {
  asm volatile(
      "global_load_dwordx4 %0, %8, off sc0 sc1\n"
      "global_load_dwordx4 %1, %9, off sc0 sc1\n"
      "global_load_dwordx4 %2, %10, off sc0 sc1\n"
      "global_load_dwordx4 %3, %11, off sc0 sc1\n"
      "global_load_dwordx4 %4, %12, off sc0 sc1\n"
      "global_load_dwordx4 %5, %13, off sc0 sc1\n"
      "global_load_dwordx4 %6, %14, off sc0 sc1\n"
      "global_load_dwordx4 %7, %15, off sc0 sc1"
      : "=&v"(v0), "=&v"(v1), "=&v"(v2), "=&v"(v3),
        "=&v"(v4), "=&v"(v5), "=&v"(v6), "=&v"(v7)
      : "v"(a0), "v"(a1), "v"(a2), "v"(a3),
        "v"(a4), "v"(a5), "v"(a6), "v"(a7)
      : "memory");
}
__device__ __forceinline__ void waitv0() {
  asm volatile("s_waitcnt vmcnt(0)" ::: "memory");
}

// --------------------- fence-free grid barrier (flags) ---------------------
// No cache maintenance anywhere: data visibility is provided by sc0/sc1 ops,
// ordering by the vmcnt(0) drain that __syncthreads performs per wave.
__device__ __forceinline__ void gsync(uint32_t* flags, uint32_t* gen, uint32_t& lgen) {
  asm volatile("s_waitcnt vmcnt(0)" ::: "memory");  // drain this wave's stores
  __syncthreads();                                   // drains all waves
  lgen += 1u;
  if (blockIdx.x == 0) {
    if (threadIdx.x > 0) {
      uint32_t g;
      do {
        g = llc_loadu(&flags[threadIdx.x]);
        if (g >= lgen) break;
        __builtin_amdgcn_s_sleep(1);
      } while (true);
    }
    __syncthreads();
    if (threadIdx.x == 0) llc_storeu(gen, lgen);
  } else {
    if (threadIdx.x == 0) {
      llc_storeu(&flags[blockIdx.x], lgen);
      uint32_t g;
      do {
        g = llc_loadu(gen);
        if (g >= lgen) break;
        __builtin_amdgcn_s_sleep(2);
      } while (true);
    }
  }
  __syncthreads();
}

// ------------------------------ init ---------------------------------------
__global__ void init_kernel(float* statebase, int nstate) {
  int i = blockIdx.x * blockDim.x + threadIdx.x;
  if (i < nstate) statebase[i] = 0.0f;
}

// --------------------------- prenet (all t) --------------------------------
__global__ __launch_bounds__(256) void prenet_kernel(
    const float* __restrict__ tmels, const float* __restrict__ W1,
    const float* __restrict__ b1, const float* __restrict__ W2,
    const float* __restrict__ b2, float* __restrict__ P_all) {
  __shared__ float melsh[MELD];
  __shared__ float h1sh[PRED];
  int blk = blockIdx.x, tid = threadIdx.x;
  int t = blk >> 5, b = blk & 31;
  if (tid < MELD)
    melsh[tid] = (t == 0) ? 0.0f : tmels[((size_t)b * TT + (t - 1)) * MELD + tid];
  __syncthreads();
  uint32_t k10, k11, k20, k21;
  subkey(t, 0, k10, k11);
  subkey(t, 1, k20, k21);
  {
    const float* wr = W1 + (size_t)tid * MELD;
    float acc = b1[tid];
    for (int m = 0; m < MELD; ++m) acc += melsh[m] * wr[m];
    acc = fmaxf(acc, 0.0f);
    bool kp = keep_draw(k10, k11, (uint32_t)(b * PRED + tid), 0.5f);
    h1sh[tid] = kp ? (acc / 0.5f) : 0.0f;
  }
  __syncthreads();
  {
    const float* wr = W2 + (size_t)tid * PRED;
    float acc = b2[tid];
    for (int k = 0; k < PRED; ++k) acc += h1sh[k] * wr[k];
    acc = fmaxf(acc, 0.0f);
    bool kp = keep_draw(k20, k21, (uint32_t)(b * PRED + tid), 0.5f);
    P_all[((size_t)t * BB + b) * PRED + tid] = kp ? (acc / 0.5f) : 0.0f;
  }
}

// ------------------------------ mem_proj -----------------------------------
__global__ __launch_bounds__(128) void memproj_kernel(
    const float* __restrict__ emb, const float* __restrict__ Wmem,
    float* __restrict__ mp) {
  __shared__ float esh[EMBD];
  int blk = blockIdx.x, tid = threadIdx.x;   // blk = b*S + s
  const float* er = emb + (size_t)blk * EMBD;
  esh[tid] = er[tid];
  esh[tid + 128] = er[tid + 128];
  __syncthreads();
  const float4* wr = (const float4*)(Wmem + (size_t)tid * EMBD);
  const float4* xr = (const float4*)esh;
  float acc = 0.0f;
  for (int k4 = 0; k4 < EMBD / 4; ++k4) {
    float4 w = wr[k4], x = xr[k4];
    acc += w.x * x.x + w.y * x.y + w.z * x.z + w.w * x.w;
  }
  mp[(size_t)blk * ATTD + tid] = acc;
}

// ------------------------------- params ------------------------------------
struct DecParams {
  const float *emb, *tmels;
  const float *Wih_pre, *Whh_pre, *bih_pre, *bhh_pre;
  const float *Wq, *conv_w, *Wloc, *vvec;
  const float *Wih_post, *Whh_post, *bih_post, *bhh_post;
  const float *Wmel, *bmel, *Wstop, *bstop;
  float *out;
  float *memproj, *P_all;
  float *Apre0, *Apre1, *Bpre0, *Bpre1;
  float *Apost0, *Apost1, *Bpost0, *Bpost1;
  float *ctx0, *ctx1, *aw0, *aw1, *asum0, *asum1;
  float *energ;
  uint32_t *flags;     // [256] arrival flags + [256] = gen
};

// ---------------------------------------------------------------------------
__global__ __launch_bounds__(256) void decoder_persistent(DecParams p) {
  __shared__ __align__(16) float smem[16384];   // 64 KB, unioned per phase
  const int blk = blockIdx.x;
  const int tid = threadIdx.x;
  uint32_t* flags = p.flags;
  uint32_t* gen = p.flags + NBLK;
  uint32_t lgen = 0u;

  for (int t = 0; t <= TT; ++t) {
    const int rr = t & 1;
    const float* Apre_r  = rr ? p.Apre1  : p.Apre0;
    const float* Bpre_r  = rr ? p.Bpre1  : p.Bpre0;
    float*       Apre_w  = rr ? p.Apre0  : p.Apre1;
    float*       Bpre_w  = rr ? p.Bpre0  : p.Bpre1;
    const float* Apost_r = rr ? p.Apost0 : p.Apost1;
    const float* Bpost_r = rr ? p.Bpost0 : p.Bpost1;
    float*       Apost_w = rr ? p.Apost1 : p.Apost0;
    float*       Bpost_w = rr ? p.Bpost1 : p.Bpost0;
    const float* ctx_r   = rr ? p.ctx1   : p.ctx0;
    float*       ctx_w   = rr ? p.ctx0   : p.ctx1;
    const float* aw_r    = rr ? p.aw1    : p.aw0;
    float*       aw_w    = rr ? p.aw0    : p.aw1;
    const float* asum_r  = rr ? p.asum1  : p.asum0;
    float*       asum_w  = rr ? p.asum0  : p.asum1;

    // ---------------- phase A: lstm1(t) [blk<128] + lstm2(t-1) -------------
    {
      const bool is1 = (blk < 128);
      const bool active = is1 ? (t < TT) : (t > 0);
      if (active) {
        const int tstep = is1 ? t : (t - 1);
        const int hb = (is1 ? blk : blk - 128) * 8;
        const int col = tid & 31;
        const int lq  = tid >> 5;
        const int b0  = lq * 4;
        const int gate = col >> 3;
        const int hl   = col & 7;
        const int gcol = gate * RNND + hb + hl;
        const int nchunks = is1 ? 6 : 9;
        const int k4c   = tid & 63;     // float4 index within 256-float chunk
        const int bbase = tid >> 6;     // 0..3

        auto srcptr = [&](int ch, int bb) -> const float4* {
          const float* s;
          if (is1) {
            if (ch == 0)      s = p.P_all + ((size_t)t * BB + bb) * PRED;
            else if (ch == 1) s = ctx_r + (size_t)bb * EMBD;
            else              s = Apre_r + (size_t)bb * RNND + (ch - 2) * 256;
          } else {
            if (ch < 4)       s = Bpre_r + (size_t)bb * RNND + ch * 256;
            else if (ch == 4) s = ctx_r + (size_t)bb * EMBD;
            else              s = Apost_r + (size_t)bb * RNND + (ch - 5) * 256;
          }
          return ((const float4*)s) + k4c;
        };

        float4 r0, r1, r2, r3, r4, r5, r6, r7;
        auto issue = [&](int ch) {
          llc_issue8(srcptr(ch, bbase), srcptr(ch, bbase + 4),
                     srcptr(ch, bbase + 8), srcptr(ch, bbase + 12),
                     srcptr(ch, bbase + 16), srcptr(ch, bbase + 20),
                     srcptr(ch, bbase + 24), srcptr(ch, bbase + 28),
                     r0, r1, r2, r3, r4, r5, r6, r7);
        };

        float acc0 = 0.f, acc1 = 0.f, acc2 = 0.f, acc3 = 0.f;
        issue(0);
        for (int ch = 0; ch < nchunks; ++ch) {
          const int buf = ch & 1;
          waitv0();
          {
            float4* xb = (float4*)(smem + buf * 8192);
            xb[(bbase +  0) * 64 + k4c] = r0;
            xb[(bbase +  4) * 64 + k4c] = r1;
            xb[(bbase +  8) * 64 + k4c] = r2;
            xb[(bbase + 12) * 64 + k4c] = r3;
            xb[(bbase + 16) * 64 + k4c] = r4;
            xb[(bbase + 20) * 64 + k4c] = r5;
            xb[(bbase + 24) * 64 + k4c] = r6;
            xb[(bbase + 28) * 64 + k4c] = r7;
          }
          __syncthreads();
          if (ch + 1 < nchunks) issue(ch + 1);

          const float* wrow;
          if (is1) wrow = (ch < 2) ? (p.Wih_pre + (size_t)gcol * 512 + ch * 256)
                                   : (p.Whh_pre + (size_t)gcol * 1024 + (ch - 2) * 256);
          else     wrow = (ch < 5) ? (p.Wih_post + (size_t)gcol * 1280 + ch * 256)
                                   : (p.Whh_post + (size_t)gcol * 1024 + (ch - 5) * 256);
          const nfloat4* w4p = (const nfloat4*)wrow;
          const float* xbf = smem + buf * 8192;
#pragma unroll 16
          for (int k4 = 0; k4 < 64; ++k4) {
            nfloat4 w = __builtin_nontemporal_load(w4p + k4);
            float4 xa = *(((const float4*)(xbf + (b0 + 0) * 256)) + k4);
            float4 xb2 = *(((const float4*)(xbf + (b0 + 1) * 256)) + k4);
            float4 xc = *(((const float4*)(xbf + (b0 + 2) * 256)) + k4);
            float4 xd = *(((const float4*)(xbf + (b0 + 3) * 256)) + k4);
            acc0 += w.x * xa.x + w.y * xa.y + w.z * xa.z + w.w * xa.w;
            acc1 += w.x * xb2.x + w.y * xb2.y + w.z * xb2.z + w.w * xb2.w;
            acc2 += w.x * xc.x + w.y * xc.y + w.z * xc.z + w.w * xc.w;
            acc3 += w.x * xd.x + w.y * xd.y + w.z * xd.z + w.w * xd.w;
          }
        }

        float bsum = is1 ? (p.bih_pre[gcol] + p.bhh_pre[gcol])
                         : (p.bih_post[gcol] + p.bhh_post[gcol]);
        acc0 += bsum; acc1 += bsum; acc2 += bsum; acc3 += bsum;

        int lane = tid & 63;
        float f0 = __shfl(acc0, lane + 8),  f1 = __shfl(acc1, lane + 8);
        float f2 = __shfl(acc2, lane + 8),  f3 = __shfl(acc3, lane + 8);
        float g0 = __shfl(acc0, lane + 16), g1 = __shfl(acc1, lane + 16);
        float g2 = __shfl(acc2, lane + 16), g3 = __shfl(acc3, lane + 16);
        float q0 = __shfl(acc0, lane + 24), q1 = __shfl(acc1, lane + 24);
        float q2 = __shfl(acc2, lane + 24), q3 = __shfl(acc3, lane + 24);

        if (gate == 0) {
          uint32_t kk0, kk1;
          subkey(tstep, is1 ? 2 : 3, kk0, kk1);
          const int h = hb + hl;
          const float* Bold = is1 ? Bpre_r : Bpost_r;
          float* Aw = is1 ? Apre_w : Apost_w;
          float* Bw = is1 ? Bpre_w : Bpost_w;
          float c0, c1, c2, c3;
          llc_load1x4(Bold + (size_t)(b0 + 0) * RNND + h,
                      Bold + (size_t)(b0 + 1) * RNND + h,
                      Bold + (size_t)(b0 + 2) * RNND + h,
                      Bold + (size_t)(b0 + 3) * RNND + h, c0, c1, c2, c3);
          float ia[4] = {acc0, acc1, acc2, acc3};
          float fa[4] = {f0, f1, f2, f3};
          float ga[4] = {g0, g1, g2, g3};
          float oa[4] = {q0, q1, q2, q3};
          float ca[4] = {c0, c1, c2, c3};
#pragma unroll
          for (int i2 = 0; i2 < 4; ++i2) {
            int bb = b0 + i2;
            float iv = sigm(ia[i2]);
            float fv = sigm(fa[i2]);
            float gv = tanhf(ga[i2]);
            float ov = sigm(oa[i2]);
            float c_new = fv * ca[i2] + iv * gv;
            float h_new = ov * tanhf(c_new);
            bool kp = keep_draw(kk0, kk1, (uint32_t)(bb * RNND + h), 0.9f);
            llc_store1(Aw + (size_t)bb * RNND + h, kp ? (h_new / 0.9f) : 0.0f);
            llc_store1(Bw + (size_t)bb * RNND + h, c_new);
          }
        }
      }
    }
    gsync(flags, gen, lgen);

    // -------- phase E: q-recompute + conv + energies (256 blocks) ----------
    if (t < TT) {
      float* qsh   = smem;           // 128
      float* vsh   = smem + 128;     // 128
      float* awin  = smem + 256;     // 94 (pad 96)
      float* aswin = smem + 352;     // 94 (pad 96)
      float* wlocs = smem + 448;     // 128*33 = 4224
      float* convs = smem + 4672;    // 32*62 = 1984
      float* locs  = smem + 6656;    // 64*33 = 2112 -> 8768
      float* hsh   = smem + 8960;    // 1024
      float* qpart = smem + 9984;    // 256
      int b = blk >> 3, st = blk & 7, s0 = st * 64;
      {
        float4 hv = llc_load4(((const float4*)(Bpre_w + (size_t)b * RNND)) + tid);
        ((float4*)hsh)[tid] = hv;
      }
      if (tid < ATTD) vsh[tid] = p.vvec[tid];
      if (tid < 94) {
        int sg = s0 - 15 + tid;
        bool ok = (sg >= 0) && (sg < SS);
        float av = 0.0f, sv = 0.0f;
        if (ok) llc_load1x2(&aw_r[b * SS + sg], &asum_r[b * SS + sg], av, sv);
        awin[tid]  = av;
        aswin[tid] = sv;
      }
      for (int idx = tid; idx < ATTD * 32; idx += 256) {
        int a = idx >> 5, c = idx & 31;
        wlocs[a * 33 + c] = p.Wloc[a * 32 + c];
      }
      for (int idx = tid; idx < 32 * 62; idx += 256) convs[idx] = p.conv_w[idx];
      __syncthreads();
      // q[b, a] recompute: 256 threads = 128 a x 2 K-halves
      {
        int a = tid & 127, half = tid >> 7;
        const float4* wr = ((const float4*)(p.Wq + (size_t)a * RNND)) + half * 128;
        const float4* xr = ((const float4*)hsh) + half * 128;
        float acc = 0.0f;
        for (int k4 = 0; k4 < 128; ++k4) {
          float4 w = wr[k4], x = xr[k4];
          acc += w.x * x.x + w.y * x.y + w.z * x.z + w.w * x.w;
        }
        qpart[half * 128 + a] = acc;
      }
      __syncthreads();
      if (tid < 128) qsh[tid] = qpart[tid] + qpart[128 + tid];
      // conv: loc[s][c], ch0 = a_sum, ch1 = a_w, kernel 31, pad 15
      for (int idx = tid; idx < 64 * 32; idx += 256) {
        int sl = idx & 63, c = idx >> 6;
        const float* cw0 = &convs[c * 62];
        const float* cw1 = &convs[c * 62 + 31];
        float acc = 0.0f;
        for (int k = 0; k < 31; ++k)
          acc += cw0[k] * aswin[sl + k] + cw1[k] * awin[sl + k];
        locs[sl * 33 + c] = acc;
      }
      __syncthreads();
      int sl = tid >> 2, aq = tid & 3, sg = s0 + sl;
      const float* mp = p.memproj + ((size_t)b * SS + sg) * ATTD;
      float acc = 0.0f;
      const float* ls = &locs[sl * 33];
      for (int j = 0; j < 32; ++j) {
        int a = j * 4 + aq;
        const float* wl = &wlocs[a * 33];
        float lp = 0.0f;
#pragma unroll 8
        for (int c = 0; c < 32; ++c) lp += ls[c] * wl[c];
        acc += vsh[a] * tanhf(qsh[a] + mp[a] + lp);
      }
      acc += __shfl_down(acc, 2);
      acc += __shfl_down(acc, 1);
      if (aq == 0) llc_store1(&p.energ[b * SS + sg], acc);
    }
    gsync(flags, gen, lgen);

    // ------- phase C: softmax+context (blk<128) | outproj (128..159) -------
    if (t < TT && blk < 128) {
      float* psh   = smem;           // 512
      float* red   = smem + 512;     // 256
      float (*cpart)[64] = (float (*)[64])(smem + 768);  // 4 x 64
      int b = blk >> 2, ec = blk & 3;
      float e1, e2;
      llc_load1x2(&p.energ[b * SS + tid], &p.energ[b * SS + 256 + tid], e1, e2);
      red[tid] = fmaxf(e1, e2);
      __syncthreads();
      for (int s = 128; s > 0; s >>= 1) {
        if (tid < s) red[tid] = fmaxf(red[tid], red[tid + s]);
        __syncthreads();
      }
      float mx = red[0];
      __syncthreads();
      float p1 = expf(e1 - mx), p2 = expf(e2 - mx);
      psh[tid] = p1; psh[tid + 256] = p2;
      red[tid] = p1 + p2;
      __syncthreads();
      for (int s = 128; s > 0; s >>= 1) {
        if (tid < s) red[tid] += red[tid + s];
        __syncthreads();
      }
      float inv = 1.0f / red[0];
      int el = tid & 63, sq = tid >> 6;
      int e = ec * 64 + el;
      float acc = 0.0f;
      const float* ebase = p.emb + ((size_t)b * SS) * EMBD + e;
      for (int s = sq * 128; s < sq * 128 + 128; ++s)
        acc += psh[s] * ebase[(size_t)s * EMBD];
      cpart[sq][el] = acc;
      __syncthreads();
      if (tid < 64)
        llc_store1(&ctx_w[b * EMBD + ec * 64 + tid],
                   (cpart[0][tid] + cpart[1][tid] + cpart[2][tid] + cpart[3][tid]) * inv);
      if (ec == 0) {
        float a1 = p1 * inv, a2 = p2 * inv;
        float s1, s2;
        llc_load1x2(&asum_r[b * SS + tid], &asum_r[b * SS + 256 + tid], s1, s2);
        llc_store1(&aw_w[b * SS + tid], a1);
        llc_store1(&aw_w[b * SS + 256 + tid], a2);
        llc_store1(&asum_w[b * SS + tid], s1 + a1);
        llc_store1(&asum_w[b * SS + 256 + tid], s2 + a2);
      }
    } else if (t > 0 && blk >= 128 && blk < 160) {
      // outproj for frame t-1: out = sigmoid([h_post, ctx] @ W^T + b)
      float* xall = smem;            // 1024 + 256
      int b = blk - 128;
      int t_prev = t - 1;
      {
        float4 hv = llc_load4(((const float4*)(Bpost_w + (size_t)b * RNND)) + tid);
        ((float4*)xall)[tid] = hv;
        if (tid < 64) {
          float4 cv = llc_load4(((const float4*)(ctx_r + (size_t)b * EMBD)) + tid);
          ((float4*)(xall + RNND))[tid] = cv;
        }
      }
      __syncthreads();
      int o = tid;
      if (o <= 80) {
        const float* wrow = (o < 80) ? (p.Wmel + (size_t)o * 1280) : p.Wstop;
        const float4* w4 = (const float4*)wrow;
        const float4* x4 = (const float4*)xall;
        float acc = 0.0f;
        for (int k4 = 0; k4 < 320; ++k4) {
          float4 w = w4[k4], x = x4[k4];
          acc += w.x * x.x + w.y * x.y + w.z * x.z + w.w * x.w;
        }
        acc += (o < 80) ? p.bmel[o] : p.bstop[0];
        float val = sigm(acc);
        if (o < 80)
          p.out[(size_t)b * (TT * MELD) + (size_t)t_prev * MELD + o] = val;
        else
          p.out[(size_t)BB * TT * MELD + (size_t)b * TT + t_prev] = val;
      }
    }
    gsync(flags, gen, lgen);
  }
}

// ------------------------------- launch ------------------------------------
extern "C" void kernel_launch(void* const* d_in, const int* in_sizes, int n_in,
                              void* d_out, int out_size, void* d_ws, size_t ws_size,
                              hipStream_t stream) {
  DecParams hp;
  hp.emb      = (const float*)d_in[0];
  hp.tmels    = (const float*)d_in[1];
  const float* W1 = (const float*)d_in[2];
  const float* b1 = (const float*)d_in[3];
  const float* W2 = (const float*)d_in[4];
  const float* b2 = (const float*)d_in[5];
  hp.Wih_pre  = (const float*)d_in[6];
  hp.Whh_pre  = (const float*)d_in[7];
  hp.bih_pre  = (const float*)d_in[8];
  hp.bhh_pre  = (const float*)d_in[9];
  hp.Wq       = (const float*)d_in[10];
  const float* Wmem = (const float*)d_in[11];
  hp.conv_w   = (const float*)d_in[12];
  hp.Wloc     = (const float*)d_in[13];
  hp.vvec     = (const float*)d_in[14];
  hp.Wih_post = (const float*)d_in[15];
  hp.Whh_post = (const float*)d_in[16];
  hp.bih_post = (const float*)d_in[17];
  hp.bhh_post = (const float*)d_in[18];
  hp.Wmel     = (const float*)d_in[19];
  hp.bmel     = (const float*)d_in[20];
  hp.Wstop    = (const float*)d_in[21];
  hp.bstop    = (const float*)d_in[22];
  hp.out = (float*)d_out;

  float* w = (float*)d_ws;
  size_t off = 0;
  auto carve = [&](size_t n) {
    float* ptr = w + off;
    off += (n + 63) & ~((size_t)63);
    return ptr;
  };
  hp.memproj = carve((size_t)BB * SS * ATTD);
  hp.P_all   = carve((size_t)TT * BB * PRED);
  size_t state_begin = off;
  hp.Apre0  = carve(BB * RNND); hp.Apre1  = carve(BB * RNND);
  hp.Bpre0  = carve(BB * RNND); hp.Bpre1  = carve(BB * RNND);
  hp.Apost0 = carve(BB * RNND); hp.Apost1 = carve(BB * RNND);
  hp.Bpost0 = carve(BB * RNND); hp.Bpost1 = carve(BB * RNND);
  hp.ctx0   = carve(BB * EMBD); hp.ctx1   = carve(BB * EMBD);
  hp.aw0    = carve(BB * SS);   hp.aw1    = carve(BB * SS);
  hp.asum0  = carve(BB * SS);   hp.asum1  = carve(BB * SS);
  hp.energ  = carve(BB * SS);
  hp.flags  = (uint32_t*)carve(512);
  size_t state_end = off;
  int nstate = (int)(state_end - state_begin);

  init_kernel<<<(nstate + 255) / 256, 256, 0, stream>>>(w + state_begin, nstate);
  prenet_kernel<<<TT * BB, 256, 0, stream>>>(hp.tmels, W1, b1, W2, b2, hp.P_all);
  memproj_kernel<<<BB * SS, 128, 0, stream>>>(hp.emb, Wmem, hp.memproj);
  decoder_persistent<<<NBLK, 256, 0, stream>>>(hp);

  (void)in_sizes; (void)n_in; (void)out_size; (void)ws_size;
}

// Round 6
// 68853.156 us; speedup vs baseline: 2.5015x; 1.3811x over previous
//
#include <hip/hip_runtime.h>
#include <cstdint>
#include <cstddef>

// ---------------------------------------------------------------------------
// Tacotron2-style decoder. Persistent kernel (256 blocks x 256 threads,
// 1 block/CU, __launch_bounds__(256,1) => 512 VGPR/thread) with LSTM weights
// held in VGPRs for all 400 steps (persistent-RNN). Fence-free LLC barrier
// (sc0/sc1) so per-XCD L2 stays warm for memproj/emb/Wq. c-state lives in a
// register. 3 barriers/step. fp32 throughout.
// ---------------------------------------------------------------------------

#define BB   32
#define SS   512
#define EMBD 256
#define MELD 80
#define PRED 256
#define RNND 1024
#define ATTD 128
#define TT   400
#define NBLK 256

// ------------------------------- threefry ---------------------------------
__device__ __forceinline__ void tf_block(uint32_t k0, uint32_t k1,
                                         uint32_t x0, uint32_t x1,
                                         uint32_t& o0, uint32_t& o1) {
  uint32_t ks2 = k0 ^ k1 ^ 0x1BD11BDAu;
  x0 += k0; x1 += k1;
#define TFR(r) { x0 += x1; x1 = (x1 << (r)) | (x1 >> (32 - (r))); x1 ^= x0; }
  TFR(13) TFR(15) TFR(26) TFR(6)
  x0 += k1;  x1 += ks2 + 1u;
  TFR(17) TFR(29) TFR(16) TFR(24)
  x0 += ks2; x1 += k0 + 2u;
  TFR(13) TFR(15) TFR(26) TFR(6)
  x0 += k0;  x1 += k1 + 3u;
  TFR(17) TFR(29) TFR(16) TFR(24)
  x0 += k1;  x1 += ks2 + 4u;
  TFR(13) TFR(15) TFR(26) TFR(6)
  x0 += ks2; x1 += k0 + 5u;
#undef TFR
  o0 = x0; o1 = x1;
}

__device__ __forceinline__ void subkey(int t, int j, uint32_t& k0, uint32_t& k1) {
  uint32_t a, b;
  tf_block(0u, 42u, 0u, (uint32_t)t, a, b);   // fold_in
  tf_block(a, b, 0u, (uint32_t)j, k0, k1);    // partitionable split
}

__device__ __forceinline__ bool keep_draw(uint32_t k0, uint32_t k1,
                                          uint32_t idx, float pkeep) {
  uint32_t o0, o1;
  tf_block(k0, k1, 0u, idx, o0, o1);
  uint32_t bits = o0 ^ o1;
  float u = __uint_as_float((bits >> 9) | 0x3f800000u) - 1.0f;
  return u < pkeep;
}

__device__ __forceinline__ float sigm(float x) { return 1.0f / (1.0f + expf(-x)); }

// ----------------------- LLC-coherent (sc0 sc1) ops ------------------------
__device__ __forceinline__ float llc_load1(const float* p) {
  float v;
  asm volatile("global_load_dword %0, %1, off sc0 sc1\ns_waitcnt vmcnt(0)"
               : "=v"(v) : "v"(p) : "memory");
  return v;
}
__device__ __forceinline__ void llc_load1x2(const float* p0, const float* p1,
                                            float& v0, float& v1) {
  asm volatile(
      "global_load_dword %0, %2, off sc0 sc1\n"
      "global_load_dword %1, %3, off sc0 sc1\n"
      "s_waitcnt vmcnt(0)"
      : "=&v"(v0), "=&v"(v1) : "v"(p0), "v"(p1) : "memory");
}
__device__ __forceinline__ float4 llc_load4(const float4* p) {
  float4 v;
  asm volatile("global_load_dwordx4 %0, %1, off sc0 sc1\ns_waitcnt vmcnt(0)"
               : "=v"(v) : "v"(p) : "memory");
  return v;
}
__device__ __forceinline__ void llc_store1(float* p, float v) {
  asm volatile("global_store_dword %0, %1, off sc0 sc1" :: "v"(p), "v"(v) : "memory");
}
__device__ __forceinline__ uint32_t llc_loadu(const uint32_t* p) {
  uint32_t v;
  asm volatile("global_load_dword %0, %1, off sc0 sc1\ns_waitcnt vmcnt(0)"
               : "=v"(v) : "v"(p) : "memory");
  return v;
}
__device__ __forceinline__ void llc_storeu(uint32_t* p, uint32_t v) {
  asm volatile("global_store_dword %0, %1, off sc0 sc1" :: "v"(p), "v"(v) : "memory");
}
// issue one f4 sc-load WITHOUT waiting; pair with waitv0()
__device__ __forceinline__ void llc_issue_f4(const float4* p, float4& v) {
  asm volatile("global_load_dwordx4 %0, %1, off sc0 sc1"
               : "=v"(v) : "v"(p) : "memory");
}
__device__ __forceinline__ void waitv0() {
  asm volatile("s_waitcnt vmcnt(0)" ::: "memory");
}

// --------------------- fence-free grid barrier (flags) ---------------------
__device__ __forceinline__ void gsync(uint32_t* flags, uint32_t* gen, uint32_t& lgen) {
  asm volatile("s_waitcnt vmcnt(0)" ::: "memory");
  __syncthreads();
  lgen += 1u;
  if (blockIdx.x == 0) {
    if (threadIdx.x > 0) {
      uint32_t g;
      do {
        g = llc_loadu(&flags[threadIdx.x]);
        if (g >= lgen) break;
        __builtin_amdgcn_s_sleep(1);
      } while (true);
    }
    __syncthreads();
    if (threadIdx.x == 0) llc_storeu(gen, lgen);
  } else {
    if (threadIdx.x == 0) {
      llc_storeu(&flags[blockIdx.x], lgen);
      uint32_t g;
      do {
        g = llc_loadu(gen);
        if (g >= lgen) break;
        __builtin_amdgcn_s_sleep(2);
      } while (true);
    }
  }
  __syncthreads();
}

// ------------------------------ init ---------------------------------------
__global__ void init_kernel(float* statebase, int nstate) {
  int i = blockIdx.x * blockDim.x + threadIdx.x;
  if (i < nstate) statebase[i] = 0.0f;
}

// --------------------------- prenet (all t) --------------------------------
__global__ __launch_bounds__(256) void prenet_kernel(
    const float* __restrict__ tmels, const float* __restrict__ W1,
    const float* __restrict__ b1, const float* __restrict__ W2,
    const float* __restrict__ b2, float* __restrict__ P_all) {
  __shared__ float melsh[MELD];
  __shared__ float h1sh[PRED];
  int blk = blockIdx.x, tid = threadIdx.x;
  int t = blk >> 5, b = blk & 31;
  if (tid < MELD)
    melsh[tid] = (t == 0) ? 0.0f : tmels[((size_t)b * TT + (t - 1)) * MELD + tid];
  __syncthreads();
  uint32_t k10, k11, k20, k21;
  subkey(t, 0, k10, k11);
  subkey(t, 1, k20, k21);
  {
    const float* wr = W1 + (size_t)tid * MELD;
    float acc = b1[tid];
    for (int m = 0; m < MELD; ++m) acc += melsh[m] * wr[m];
    acc = fmaxf(acc, 0.0f);
    bool kp = keep_draw(k10, k11, (uint32_t)(b * PRED + tid), 0.5f);
    h1sh[tid] = kp ? (acc / 0.5f) : 0.0f;
  }
  __syncthreads();
  {
    const float* wr = W2 + (size_t)tid * PRED;
    float acc = b2[tid];
    for (int k = 0; k < PRED; ++k) acc += h1sh[k] * wr[k];
    acc = fmaxf(acc, 0.0f);
    bool kp = keep_draw(k20, k21, (uint32_t)(b * PRED + tid), 0.5f);
    P_all[((size_t)t * BB + b) * PRED + tid] = kp ? (acc / 0.5f) : 0.0f;
  }
}

// ------------------------------ mem_proj -----------------------------------
__global__ __launch_bounds__(128) void memproj_kernel(
    const float* __restrict__ emb, const float* __restrict__ Wmem,
    float* __restrict__ mp) {
  __shared__ float esh[EMBD];
  int blk = blockIdx.x, tid = threadIdx.x;   // blk = b*S + s
  const float* er = emb + (size_t)blk * EMBD;
  esh[tid] = er[tid];
  esh[tid + 128] = er[tid + 128];
  __syncthreads();
  const float4* wr = (const float4*)(Wmem + (size_t)tid * EMBD);
  const float4* xr = (const float4*)esh;
  float acc = 0.0f;
  for (int k4 = 0; k4 < EMBD / 4; ++k4) {
    float4 w = wr[k4], x = xr[k4];
    acc += w.x * x.x + w.y * x.y + w.z * x.z + w.w * x.w;
  }
  mp[(size_t)blk * ATTD + tid] = acc;
}

// ------------------------------- params ------------------------------------
struct DecParams {
  const float *emb, *tmels;
  const float *Wih_pre, *Whh_pre, *bih_pre, *bhh_pre;
  const float *Wq, *conv_w, *Wloc, *vvec;
  const float *Wih_post, *Whh_post, *bih_post, *bhh_post;
  const float *Wmel, *bmel, *Wstop, *bstop;
  float *out;
  float *memproj, *P_all;
  float *Apre0, *Apre1, *Bpre0, *Bpre1;
  float *Apost0, *Apost1, *Bpost0, *Bpost1;
  float *ctx0, *ctx1, *aw0, *aw1, *asum0, *asum1;
  float *energ;
  uint32_t *flags;     // [256] arrival flags + [256] = gen
};

// ---------------- VGPR-resident weight load (one-time) ---------------------
// thread (r = tid>>5, s = tid&31) owns all 4 gates of h = hb + r, K-slice s.
template<int NJ, int SL, int KIH>
__device__ __forceinline__ void load_weights(
    float4 (&w)[4][18], float (&bs)[4], int hb, int tid,
    const float* __restrict__ Wih, const float* __restrict__ Whh,
    const float* __restrict__ bih, const float* __restrict__ bhh) {
  const int r = tid >> 5, s = tid & 31;
#pragma unroll
  for (int g = 0; g < 4; ++g) {
    int gcol = g * RNND + hb + r;
    bs[g] = bih[gcol] + bhh[gcol];
#pragma unroll
    for (int j4 = 0; j4 < NJ; ++j4) {
      float4 v4;
      {
        int k = s * SL + j4 * 4 + 0;
        v4.x = (k < KIH) ? Wih[(size_t)gcol * KIH + k] : Whh[(size_t)gcol * RNND + (k - KIH)];
      }
      {
        int k = s * SL + j4 * 4 + 1;
        v4.y = (k < KIH) ? Wih[(size_t)gcol * KIH + k] : Whh[(size_t)gcol * RNND + (k - KIH)];
      }
      {
        int k = s * SL + j4 * 4 + 2;
        v4.z = (k < KIH) ? Wih[(size_t)gcol * KIH + k] : Whh[(size_t)gcol * RNND + (k - KIH)];
      }
      {
        int k = s * SL + j4 * 4 + 3;
        v4.w = (k < KIH) ? Wih[(size_t)gcol * KIH + k] : Whh[(size_t)gcol * RNND + (k - KIH)];
      }
      w[g][j4] = v4;
    }
  }
}

// ------------------- phase A: one LSTM cell, weights in VGPRs ---------------
// x[k] layout: [0,L0): src0 (row stride S0) | [L0,L0+256): ctx | rest: srcR.
// 8 chunks of 4 batches; xs LDS padded slices (SLP); gates LDS 32b x 8h x f4.
template<int NJ, int SLP, int NL, int F4B, int L0, int S0>
__device__ __forceinline__ void lstm_phaseA(
    int tid, int hb, int tdraw, int jdraw,
    const float4 (&w)[4][18], const float (&bs)[4], float& c_state,
    const float* __restrict__ src0, const float* __restrict__ ctxp,
    const float* __restrict__ srcR,
    float* Aw, float* Bw, float* xs, float* gates) {
  const int r = tid >> 5;
  const int s = tid & 31;
  float4 rg[9];

  auto issue = [&](int c) {
#pragma unroll
    for (int i = 0; i < NL; ++i) {
      int flat = i * 256 + tid;
      int bl = flat / F4B;
      int k4 = flat - bl * F4B;
      int k = k4 * 4;
      int bg = c * 4 + bl;
      const float* sp;
      if (k < L0)            sp = src0 + (size_t)bg * S0 + k;
      else if (k < L0 + 256) sp = ctxp + bg * 256 + (k - L0);
      else                   sp = srcR + (size_t)bg * 1024 + (k - L0 - 256);
      llc_issue_f4((const float4*)sp, rg[i]);
    }
  };

  issue(0);
  for (int c = 0; c < 8; ++c) {
    __syncthreads();            // chunk c-1 compute done; LDS reusable
    waitv0();
    __builtin_amdgcn_sched_barrier(0);
#pragma unroll
    for (int i = 0; i < NL; ++i) {
      int flat = i * 256 + tid;
      int bl = flat / F4B;
      int k4 = flat - bl * F4B;
      int slice = k4 / NJ;
      int j4 = k4 - slice * NJ;
      *(float4*)(xs + (bl * 32 + slice) * SLP + j4 * 4) = rg[i];
    }
    __syncthreads();
    if (c < 7) issue(c + 1);    // prefetch next chunk under compute
#pragma unroll
    for (int bl = 0; bl < 4; ++bl) {
      const float4* xb = (const float4*)(xs + (bl * 32 + s) * SLP);
      float a0 = 0.f, a1 = 0.f, a2 = 0.f, a3 = 0.f;
#pragma unroll
      for (int j4 = 0; j4 < NJ; ++j4) {
        float4 x4 = xb[j4];
        a0 += w[0][j4].x * x4.x + w[0][j4].y * x4.y + w[0][j4].z * x4.z + w[0][j4].w * x4.w;
        a1 += w[1][j4].x * x4.x + w[1][j4].y * x4.y + w[1][j4].z * x4.z + w[1][j4].w * x4.w;
        a2 += w[2][j4].x * x4.x + w[2][j4].y * x4.y + w[2][j4].z * x4.z + w[2][j4].w * x4.w;
        a3 += w[3][j4].x * x4.x + w[3][j4].y * x4.y + w[3][j4].z * x4.z + w[3][j4].w * x4.w;
      }
#pragma unroll
      for (int m = 1; m < 32; m <<= 1) {
        a0 += __shfl_xor(a0, m);
        a1 += __shfl_xor(a1, m);
        a2 += __shfl_xor(a2, m);
        a3 += __shfl_xor(a3, m);
      }
      if (s == 0) {
        float4 g4;
        g4.x = a0 + bs[0]; g4.y = a1 + bs[1]; g4.z = a2 + bs[2]; g4.w = a3 + bs[3];
        ((float4*)gates)[(c * 4 + bl) * 8 + r] = g4;
      }
    }
  }
  __syncthreads();
  // cell update: thread (hloc = tid>>5, bb = tid&31) == (r, s): same cell
  // every step => c_state stays in a register for the whole kernel.
  {
    const int hloc = r, bb = s;
    float4 g4 = ((const float4*)gates)[bb * 8 + hloc];
    uint32_t kk0, kk1;
    subkey(tdraw, jdraw, kk0, kk1);
    float iv = sigm(g4.x), fv = sigm(g4.y), gv = tanhf(g4.z), ov = sigm(g4.w);
    float c_new = fv * c_state + iv * gv;
    c_state = c_new;
    float h_new = ov * tanhf(c_new);
    bool kp = keep_draw(kk0, kk1, (uint32_t)(bb * RNND + hb + hloc), 0.9f);
    llc_store1(Aw + (size_t)bb * RNND + hb + hloc, kp ? (h_new / 0.9f) : 0.0f);
    llc_store1(Bw + (size_t)bb * RNND + hb + hloc, c_new);
  }
}

// ---------------------------------------------------------------------------
__global__ __launch_bounds__(256, 1) void decoder_persistent(DecParams p) {
  __shared__ __align__(16) float smem[10752];   // 43 KB, unioned per phase
  const int blk = blockIdx.x;
  const int tid = threadIdx.x;
  uint32_t* flags = p.flags;
  uint32_t* gen = p.flags + NBLK;
  uint32_t lgen = 0u;

  const bool is1 = (blk < 128);
  const int hb = (is1 ? blk : blk - 128) * 8;

  // -------- one-time: weights into VGPRs --------
  float4 w[4][18];
  float bs[4];
  if (is1) load_weights<12, 48, 512>(w, bs, hb, tid, p.Wih_pre, p.Whh_pre,
                                     p.bih_pre, p.bhh_pre);
  else     load_weights<18, 72, 1280>(w, bs, hb, tid, p.Wih_post, p.Whh_post,
                                      p.bih_post, p.bhh_post);
  float c_state = 0.0f;

  for (int t = 0; t <= TT; ++t) {
    const int rr = t & 1;
    const float* Apre_r  = rr ? p.Apre1  : p.Apre0;
    const float* Bpre_r  = rr ? p.Bpre1  : p.Bpre0;
    float*       Apre_w  = rr ? p.Apre0  : p.Apre1;
    float*       Bpre_w  = rr ? p.Bpre0  : p.Bpre1;
    const float* Apost_r = rr ? p.Apost0 : p.Apost1;
    float*       Apost_w = rr ? p.Apost1 : p.Apost0;
    float*       Bpost_w = rr ? p.Bpost1 : p.Bpost0;
    const float* ctx_r   = rr ? p.ctx1   : p.ctx0;
    float*       ctx_w   = rr ? p.ctx0   : p.ctx1;
    const float* aw_r    = rr ? p.aw1    : p.aw0;
    float*       aw_w    = rr ? p.aw0    : p.aw1;
    const float* asum_r  = rr ? p.asum1  : p.asum0;
    float*       asum_w  = rr ? p.asum0  : p.asum1;

    // ---------------- phase A: lstm1(t) [blk<128] + lstm2(t-1) -------------
    if (is1) {
      if (t < TT)
        lstm_phaseA<12, 52, 6, 384, 256, 256>(
            tid, hb, t, 2, w, bs, c_state,
            p.P_all + (size_t)t * BB * PRED, ctx_r, Apre_r,
            Apre_w, Bpre_w, smem, smem + 9728);
    } else {
      if (t > 0)
        lstm_phaseA<18, 76, 9, 576, 1024, 1024>(
            tid, hb, t - 1, 3, w, bs, c_state,
            Bpre_r, ctx_r, Apost_r,
            Apost_w, Bpost_w, smem, smem + 9728);
    }
    gsync(flags, gen, lgen);

    // -------- phase E: q-recompute + conv + energies (256 blocks) ----------
    if (t < TT) {
      float* qsh   = smem;           // 128
      float* vsh   = smem + 128;     // 128
      float* awin  = smem + 256;     // 94 (pad 96)
      float* aswin = smem + 352;     // 94 (pad 96)
      float* wlocs = smem + 448;     // 128*33 = 4224
      float* convs = smem + 4672;    // 32*62 = 1984
      float* locs  = smem + 6656;    // 64*33 = 2112 -> 8768
      float* hsh   = smem + 8960;    // 1024
      float* qpart = smem + 9984;    // 256
      int b = blk >> 3, st = blk & 7, s0 = st * 64;
      {
        float4 hv = llc_load4(((const float4*)(Bpre_w + (size_t)b * RNND)) + tid);
        ((float4*)hsh)[tid] = hv;
      }
      if (tid < ATTD) vsh[tid] = p.vvec[tid];
      if (tid < 94) {
        int sg = s0 - 15 + tid;
        bool ok = (sg >= 0) && (sg < SS);
        float av = 0.0f, sv = 0.0f;
        if (ok) llc_load1x2(&aw_r[b * SS + sg], &asum_r[b * SS + sg], av, sv);
        awin[tid]  = av;
        aswin[tid] = sv;
      }
      for (int idx = tid; idx < ATTD * 32; idx += 256) {
        int a = idx >> 5, c = idx & 31;
        wlocs[a * 33 + c] = p.Wloc[a * 32 + c];
      }
      for (int idx = tid; idx < 32 * 62; idx += 256) convs[idx] = p.conv_w[idx];
      __syncthreads();
      // q[b, a] recompute: 256 threads = 128 a x 2 K-halves
      {
        int a = tid & 127, half = tid >> 7;
        const float4* wr = ((const float4*)(p.Wq + (size_t)a * RNND)) + half * 128;
        const float4* xr = ((const float4*)hsh) + half * 128;
        float acc = 0.0f;
        for (int k4 = 0; k4 < 128; ++k4) {
          float4 wv = wr[k4], x = xr[k4];
          acc += wv.x * x.x + wv.y * x.y + wv.z * x.z + wv.w * x.w;
        }
        qpart[half * 128 + a] = acc;
      }
      __syncthreads();
      if (tid < 128) qsh[tid] = qpart[tid] + qpart[128 + tid];
      // conv: loc[s][c], ch0 = a_sum, ch1 = a_w, kernel 31, pad 15
      for (int idx = tid; idx < 64 * 32; idx += 256) {
        int sl = idx & 63, c = idx >> 6;
        const float* cw0 = &convs[c * 62];
        const float* cw1 = &convs[c * 62 + 31];
        float acc = 0.0f;
        for (int k = 0; k < 31; ++k)
          acc += cw0[k] * aswin[sl + k] + cw1[k] * awin[sl + k];
        locs[sl * 33 + c] = acc;
      }
      __syncthreads();
      int sl = tid >> 2, aq = tid & 3, sg = s0 + sl;
      const float* mp = p.memproj + ((size_t)b * SS + sg) * ATTD;
      float acc = 0.0f;
      const float* ls = &locs[sl * 33];
      for (int j = 0; j < 32; ++j) {
        int a = j * 4 + aq;
        const float* wl = &wlocs[a * 33];
        float lp = 0.0f;
#pragma unroll 8
        for (int c = 0; c < 32; ++c) lp += ls[c] * wl[c];
        acc += vsh[a] * tanhf(qsh[a] + mp[a] + lp);
      }
      acc += __shfl_down(acc, 2);
      acc += __shfl_down(acc, 1);
      if (aq == 0) llc_store1(&p.energ[b * SS + sg], acc);
    }
    gsync(flags, gen, lgen);

    // ------- phase C: softmax+context (blk<128) | outproj (128..159) -------
    if (t < TT && blk < 128) {
      float* psh   = smem;           // 512
      float* red   = smem + 512;     // 256
      float (*cpart)[64] = (float (*)[64])(smem + 768);  // 4 x 64
      int b = blk >> 2, ec = blk & 3;
      float e1, e2;
      llc_load1x2(&p.energ[b * SS + tid], &p.energ[b * SS + 256 + tid], e1, e2);
      red[tid] = fmaxf(e1, e2);
      __syncthreads();
      for (int s2 = 128; s2 > 0; s2 >>= 1) {
        if (tid < s2) red[tid] = fmaxf(red[tid], red[tid + s2]);
        __syncthreads();
      }
      float mx = red[0];
      __syncthreads();
      float p1 = expf(e1 - mx), p2 = expf(e2 - mx);
      psh[tid] = p1; psh[tid + 256] = p2;
      red[tid] = p1 + p2;
      __syncthreads();
      for (int s2 = 128; s2 > 0; s2 >>= 1) {
        if (tid < s2) red[tid] += red[tid + s2];
        __syncthreads();
      }
      float inv = 1.0f / red[0];
      int el = tid & 63, sq = tid >> 6;
      int e = ec * 64 + el;
      float acc = 0.0f;
      const float* ebase = p.emb + ((size_t)b * SS) * EMBD + e;
      for (int s2 = sq * 128; s2 < sq * 128 + 128; ++s2)
        acc += psh[s2] * ebase[(size_t)s2 * EMBD];
      cpart[sq][el] = acc;
      __syncthreads();
      if (tid < 64)
        llc_store1(&ctx_w[b * EMBD + ec * 64 + tid],
                   (cpart[0][tid] + cpart[1][tid] + cpart[2][tid] + cpart[3][tid]) * inv);
      if (ec == 0) {
        float a1 = p1 * inv, a2 = p2 * inv;
        float s1, s2v;
        llc_load1x2(&asum_r[b * SS + tid], &asum_r[b * SS + 256 + tid], s1, s2v);
        llc_store1(&aw_w[b * SS + tid], a1);
        llc_store1(&aw_w[b * SS + 256 + tid], a2);
        llc_store1(&asum_w[b * SS + tid], s1 + a1);
        llc_store1(&asum_w[b * SS + 256 + tid], s2v + a2);
      }
    } else if (t > 0 && blk >= 128 && blk < 160) {
      // outproj for frame t-1: out = sigmoid([h_post, ctx] @ W^T + b)
      float* xall = smem;            // 1024 + 256
      int b = blk - 128;
      int t_prev = t - 1;
      {
        float4 hv = llc_load4(((const float4*)(Bpost_w + (size_t)b * RNND)) + tid);
        ((float4*)xall)[tid] = hv;
        if (tid < 64) {
          float4 cv = llc_load4(((const float4*)(ctx_r + (size_t)b * EMBD)) + tid);
          ((float4*)(xall + RNND))[tid] = cv;
        }
      }
      __syncthreads();
      int o = tid;
      if (o <= 80) {
        const float* wrow = (o < 80) ? (p.Wmel + (size_t)o * 1280) : p.Wstop;
        const float4* w4 = (const float4*)wrow;
        const float4* x4 = (const float4*)xall;
        float acc = 0.0f;
        for (int k4 = 0; k4 < 320; ++k4) {
          float4 wv = w4[k4], x = x4[k4];
          acc += wv.x * x.x + wv.y * x.y + wv.z * x.z + wv.w * x.w;
        }
        acc += (o < 80) ? p.bmel[o] : p.bstop[0];
        float val = sigm(acc);
        if (o < 80)
          p.out[(size_t)b * (TT * MELD) + (size_t)t_prev * MELD + o] = val;
        else
          p.out[(size_t)BB * TT * MELD + (size_t)b * TT + t_prev] = val;
      }
    }
    gsync(flags, gen, lgen);
  }
}

// ------------------------------- launch ------------------------------------
extern "C" void kernel_launch(void* const* d_in, const int* in_sizes, int n_in,
                              void* d_out, int out_size, void* d_ws, size_t ws_size,
                              hipStream_t stream) {
  DecParams hp;
  hp.emb      = (const float*)d_in[0];
  hp.tmels    = (const float*)d_in[1];
  const float* W1 = (const float*)d_in[2];
  const float* b1 = (const float*)d_in[3];
  const float* W2 = (const float*)d_in[4];
  const float* b2 = (const float*)d_in[5];
  hp.Wih_pre  = (const float*)d_in[6];
  hp.Whh_pre  = (const float*)d_in[7];
  hp.bih_pre  = (const float*)d_in[8];
  hp.bhh_pre  = (const float*)d_in[9];
  hp.Wq       = (const float*)d_in[10];
  const float* Wmem = (const float*)d_in[11];
  hp.conv_w   = (const float*)d_in[12];
  hp.Wloc     = (const float*)d_in[13];
  hp.vvec     = (const float*)d_in[14];
  hp.Wih_post = (const float*)d_in[15];
  hp.Whh_post = (const float*)d_in[16];
  hp.bih_post = (const float*)d_in[17];
  hp.bhh_post = (const float*)d_in[18];
  hp.Wmel     = (const float*)d_in[19];
  hp.bmel     = (const float*)d_in[20];
  hp.Wstop    = (const float*)d_in[21];
  hp.bstop    = (const float*)d_in[22];
  hp.out = (float*)d_out;

  float* w = (float*)d_ws;
  size_t off = 0;
  auto carve = [&](size_t n) {
    float* ptr = w + off;
    off += (n + 63) & ~((size_t)63);
    return ptr;
  };
  hp.memproj = carve((size_t)BB * SS * ATTD);
  hp.P_all   = carve((size_t)TT * BB * PRED);
  size_t state_begin = off;
  hp.Apre0  = carve(BB * RNND); hp.Apre1  = carve(BB * RNND);
  hp.Bpre0  = carve(BB * RNND); hp.Bpre1  = carve(BB * RNND);
  hp.Apost0 = carve(BB * RNND); hp.Apost1 = carve(BB * RNND);
  hp.Bpost0 = carve(BB * RNND); hp.Bpost1 = carve(BB * RNND);
  hp.ctx0   = carve(BB * EMBD); hp.ctx1   = carve(BB * EMBD);
  hp.aw0    = carve(BB * SS);   hp.aw1    = carve(BB * SS);
  hp.asum0  = carve(BB * SS);   hp.asum1  = carve(BB * SS);
  hp.energ  = carve(BB * SS);
  hp.flags  = (uint32_t*)carve(512);
  size_t state_end = off;
  int nstate = (int)(state_end - state_begin);

  init_kernel<<<(nstate + 255) / 256, 256, 0, stream>>>(w + state_begin, nstate);
  prenet_kernel<<<TT * BB, 256, 0, stream>>>(hp.tmels, W1, b1, W2, b2, hp.P_all);
  memproj_kernel<<<BB * SS, 128, 0, stream>>>(hp.emb, Wmem, hp.memproj);
  decoder_persistent<<<NBLK, 256, 0, stream>>>(hp);

  (void)in_sizes; (void)n_in; (void)out_size; (void)ws_size;
}